// Round 5
// baseline (121.545 us; speedup 1.0000x reference)
//
#include <hip/hip_runtime.h>

// SparseAttention: B=4, M=4096, N=4096, D=128, W=128, fp32 in/out.
// Round 5: same algorithm as round 4 (fp16 K gather for logits, sparse fp32 V
// gather for p >= EPS), but 4 m-rows per 512-thread block (4 independent
// 128-thread units) -> grid 16384 -> 4096. Diagnostic for the suspected
// workgroup-dispatch-rate floor (~3 ns/WG fits R1-R4 exactly).

typedef __attribute__((ext_vector_type(2))) _Float16 half2v;
typedef __attribute__((ext_vector_type(8))) _Float16 half8;

constexpr int Bc = 4, Mc = 4096, Nc = 4096, Dc = 128, Wc = 128;
constexpr int UNITS = 4;                            // m-rows per block
constexpr size_t KV_ELEMS = (size_t)Bc * Nc * Dc;   // 2,097,152 per tensor
constexpr float EPS_P = 5e-5f;

// ---- fp32 -> fp16 conversion pre-pass (K only), 8 elems/thread ----
__global__ __launch_bounds__(256) void cvt_kernel(
    const float* __restrict__ k3d, _Float16* __restrict__ kh)
{
    const size_t i = ((size_t)blockIdx.x * blockDim.x + threadIdx.x) * 8;
    if (i >= KV_ELEMS) return;
    const float4 ka = *reinterpret_cast<const float4*>(k3d + i);
    const float4 kb = *reinterpret_cast<const float4*>(k3d + i + 4);
    half8 hk;
    hk[0]=(_Float16)ka.x; hk[1]=(_Float16)ka.y; hk[2]=(_Float16)ka.z; hk[3]=(_Float16)ka.w;
    hk[4]=(_Float16)kb.x; hk[5]=(_Float16)kb.y; hk[6]=(_Float16)kb.z; hk[7]=(_Float16)kb.w;
    *reinterpret_cast<half8*>(kh + i) = hk;
}

__global__ __launch_bounds__(512, 8) void sparse_attn_f16(
    const float*    __restrict__ q3d,
    const _Float16* __restrict__ kh,
    const float*    __restrict__ v3d,
    const int*      __restrict__ cidx,
    float*          __restrict__ out)
{
    // XCD-aware decode: batch b pinned to XCD pair {2b,2b+1}; 1 MB fp16 K/batch
    // stays resident in that XCD's 4 MiB L2.
    const int blk  = blockIdx.x;          // 0..4095
    const int unit = threadIdx.x >> 7;    // 0..3
    const int t    = threadIdx.x & 127;   // 0..127 within unit
    const int xcd  = blk & 7;
    const int b    = xcd >> 1;
    const int m    = ((blk >> 3) << 3) | ((xcd & 1) << 2) | unit;

    __shared__ _Float16 qsh[UNITS][Dc];
    __shared__ int    cs[UNITS][Wc];
    __shared__ float  ls[UNITS][Wc];
    __shared__ float  wred[UNITS][2];
    __shared__ float  wred2[UNITS][2];
    __shared__ int    widx[UNITS][Wc];    // compacted: row index * 32 (float4 units)
    __shared__ float  wp[UNITS][Wc];      // compacted: weight
    __shared__ int    cnt[UNITS];
    __shared__ float4 accs[UNITS][4][32];

    qsh[unit][t] = (_Float16)q3d[((size_t)b * Mc + m) * Dc + t];
    cs[unit][t]  = cidx[m * Wc + t];
    if (t == 0) cnt[unit] = 0;
    __syncthreads();

    const int g = t >> 4;   // row-group 0..7 (phase 1)
    const int l = t & 15;   // lane-in-group: covers d = l*8 .. l*8+7

    const half8* kb = reinterpret_cast<const half8*>(kh + (size_t)b * Nc * Dc);

    const half8 qv = *reinterpret_cast<const half8*>(&qsh[unit][l * 8]);
    const half2v q0 = {qv[0], qv[1]}, q1 = {qv[2], qv[3]},
                 q2 = {qv[4], qv[5]}, q3 = {qv[6], qv[7]};

    // ---- Phase 1: all 128 logits via v_dot2_f32_f16 ----
    #pragma unroll 8
    for (int it = 0; it < 16; ++it) {
        const int w = it * 8 + g;
        const half8 kv = kb[cs[unit][w] * 16 + l];
        const half2v k0 = {kv[0], kv[1]}, k1 = {kv[2], kv[3]},
                     k2 = {kv[4], kv[5]}, k3 = {kv[6], kv[7]};
        float p = __builtin_amdgcn_fdot2(q0, k0, 0.f, false);
        p = __builtin_amdgcn_fdot2(q1, k1, p, false);
        p = __builtin_amdgcn_fdot2(q2, k2, p, false);
        p = __builtin_amdgcn_fdot2(q3, k3, p, false);
        p += __shfl_xor(p, 8);
        p += __shfl_xor(p, 4);
        p += __shfl_xor(p, 2);
        p += __shfl_xor(p, 1);
        if (l == 0) ls[unit][w] = p;
    }
    __syncthreads();

    // ---- Softmax over 128 logits (exact denominator over ALL rows) ----
    float L = ls[unit][t];
    float mx = L;
    #pragma unroll
    for (int o = 32; o; o >>= 1) mx = fmaxf(mx, __shfl_xor(mx, o));
    if ((t & 63) == 0) wred[unit][t >> 6] = mx;
    __syncthreads();
    mx = fmaxf(wred[unit][0], wred[unit][1]);
    const float e = __expf(L - mx);
    float s = e;
    #pragma unroll
    for (int o = 32; o; o >>= 1) s += __shfl_xor(s, o);
    if ((t & 63) == 0) wred2[unit][t >> 6] = s;
    __syncthreads();
    s = wred2[unit][0] + wred2[unit][1];
    const float p = e / s;

    // ---- Compact the significant rows (typically ~6 of 128) ----
    if (p >= EPS_P) {
        const int slot = atomicAdd(&cnt[unit], 1);
        widx[unit][slot] = cs[unit][t] * 32;   // float4-unit offset of the V row
        wp[unit][slot]   = p;
    }
    __syncthreads();
    const int n = cnt[unit];                   // >= 1 always (max p >= 1/128)

    // ---- Phase 2: sparse V gather, fp32 exact. Quarter x float4 = one row. ----
    const int q32 = t >> 5;   // quarter 0..3
    const int l32 = t & 31;   // covers d = l32*4 .. l32*4+3
    const float4* vb = reinterpret_cast<const float4*>(v3d + (size_t)b * Nc * Dc);

    float4 acc = {0.f, 0.f, 0.f, 0.f};
    for (int e2 = q32; e2 < n; e2 += 4) {
        const float pw = wp[unit][e2];
        const float4 v4 = vb[widx[unit][e2] + l32];
        acc.x += pw * v4.x;
        acc.y += pw * v4.y;
        acc.z += pw * v4.z;
        acc.w += pw * v4.w;
    }
    accs[unit][q32][l32] = acc;
    __syncthreads();

    if (t < 32) {
        const float4 a0 = accs[unit][0][t], a1 = accs[unit][1][t],
                     a2 = accs[unit][2][t], a3 = accs[unit][3][t];
        float4 o;
        o.x = a0.x + a1.x + a2.x + a3.x;
        o.y = a0.y + a1.y + a2.y + a3.y;
        o.z = a0.z + a1.z + a2.z + a3.z;
        o.w = a0.w + a1.w + a2.w + a3.w;
        reinterpret_cast<float4*>(out + ((size_t)b * Mc + m) * Dc)[t] = o;
    }
}

extern "C" void kernel_launch(void* const* d_in, const int* in_sizes, int n_in,
                              void* d_out, int out_size, void* d_ws, size_t ws_size,
                              hipStream_t stream) {
    const float* q = (const float*)d_in[0];
    const float* k = (const float*)d_in[1];
    const float* v = (const float*)d_in[2];
    const int*   c = (const int*)d_in[3];
    float*       o = (float*)d_out;
    (void)in_sizes; (void)n_in; (void)out_size; (void)ws_size;

    _Float16* kh = (_Float16*)d_ws;            // 4 MB

    const int cvt_threads = 256;
    const int cvt_blocks  = (int)(KV_ELEMS / 8 / cvt_threads);   // 1024
    cvt_kernel<<<cvt_blocks, cvt_threads, 0, stream>>>(k, kh);

    sparse_attn_f16<<<dim3(Bc * Mc / UNITS), dim3(128 * UNITS), 0, stream>>>(q, kh, v, c, o);
}